// Round 1
// baseline (158.971 us; speedup 1.0000x reference)
//
#include <hip/hip_runtime.h>
#include <stdint.h>

typedef __attribute__((ext_vector_type(8))) short  bf16x8;
typedef __attribute__((ext_vector_type(4))) short  short4v;
typedef __attribute__((ext_vector_type(4))) float  f32x4;
typedef __attribute__((ext_vector_type(4))) float  float4v;

__device__ __forceinline__ unsigned short f2bf(float f) {
  unsigned int u = __builtin_bit_cast(unsigned int, f);
  u += 0x7FFFu + ((u >> 16) & 1u);          // round-to-nearest-even
  return (unsigned short)(u >> 16);
}

__device__ __forceinline__ void async_ld16(const void* g, void* l) {
  __builtin_amdgcn_global_load_lds(
      (const __attribute__((address_space(1))) void*)g,
      (__attribute__((address_space(3))) void*)l,
      16, 0, 0);
}

// ---------------------------------------------------------------- casts ----
__global__ __launch_bounds__(256) void cast4_bf16(
    const float* __restrict__ in, unsigned short* __restrict__ out, int n4) {
  int i = blockIdx.x * 256 + threadIdx.x;
  if (i >= n4) return;
  float4v v = *(const float4v*)(in + (size_t)i * 4);
  short4v o;
  o[0] = (short)f2bf(v[0]); o[1] = (short)f2bf(v[1]);
  o[2] = (short)f2bf(v[2]); o[3] = (short)f2bf(v[3]);
  *(short4v*)(out + (size_t)i * 4) = o;
}

// in: R x C fp32 (row-major)  ->  out: C x R bf16 (row-major) == in^T
__global__ __launch_bounds__(256) void transpose_cast(
    const float* __restrict__ in, unsigned short* __restrict__ out,
    int R, int C) {
  __shared__ float tile[32][33];
  const int tx = threadIdx.x & 31, ty = threadIdx.x >> 5;   // 32 x 8
  const int c0 = blockIdx.x * 32, r0 = blockIdx.y * 32;
  #pragma unroll
  for (int rr = ty; rr < 32; rr += 8)
    tile[rr][tx] = in[(size_t)(r0 + rr) * C + c0 + tx];
  __syncthreads();
  #pragma unroll
  for (int cc = ty; cc < 32; cc += 8)
    out[(size_t)(c0 + cc) * R + r0 + tx] = f2bf(tile[tx][cc]);
}

// ---------------------------------------------------------------- GEMM -----
// C[M,N] = A[M,K] * BT[N,K]^T ; m97-style: 128x128 tile, BK=32, 4 waves.
template<int BF16_OUT>
__global__ __launch_bounds__(256) void gemm_bt(
    const unsigned short* __restrict__ A,
    const unsigned short* __restrict__ BT,
    void* __restrict__ Cout,
    const float* __restrict__ bias,
    int M, int N, int K) {
  __shared__ __align__(16) unsigned short lsA[128 * 32];
  __shared__ __align__(16) unsigned short lsB[128 * 32];
  const int tid = threadIdx.x;
  const int wv = tid >> 6, ln = tid & 63;
  const int bm = blockIdx.y * 128, bn = blockIdx.x * 128;
  const int wr = (wv >> 1) * 64, wc = (wv & 1) * 64;

  f32x4 acc[4][4] = {};

  // staging: per wave-call 1024B contiguous LDS chunk; lane lambda -> +16B*lambda
  const int srow = wv * 16 + (ln >> 2);     // 0..63
  const int scol = (ln & 3) * 8;            // k-element offset
  const unsigned short* gA0 = A  + (size_t)(bm + srow) * K + scol;
  const unsigned short* gA1 = gA0 + (size_t)64 * K;
  const unsigned short* gB0 = BT + (size_t)(bn + srow) * K + scol;
  const unsigned short* gB1 = gB0 + (size_t)64 * K;
  unsigned short* lA0 = &lsA[srow * 32 + scol];
  unsigned short* lA1 = &lsA[(64 + srow) * 32 + scol];
  unsigned short* lB0 = &lsB[srow * 32 + scol];
  unsigned short* lB1 = &lsB[(64 + srow) * 32 + scol];

  const int fra = wr + (ln & 15);
  const int frb = wc + (ln & 15);
  const int ko  = (ln >> 4) * 8;

  for (int k0 = 0; k0 < K; k0 += 32) {
    async_ld16(gA0 + k0, lA0);
    async_ld16(gA1 + k0, lA1);
    async_ld16(gB0 + k0, lB0);
    async_ld16(gB1 + k0, lB1);
    __syncthreads();
    bf16x8 af[4], bfr[4];
    #pragma unroll
    for (int m = 0; m < 4; m++) af[m]  = *(const bf16x8*)&lsA[(fra + m * 16) * 32 + ko];
    #pragma unroll
    for (int n = 0; n < 4; n++) bfr[n] = *(const bf16x8*)&lsB[(frb + n * 16) * 32 + ko];
    #pragma unroll
    for (int m = 0; m < 4; m++)
      #pragma unroll
      for (int n = 0; n < 4; n++)
        acc[m][n] = __builtin_amdgcn_mfma_f32_16x16x32_bf16(af[m], bfr[n], acc[m][n], 0, 0, 0);
    __syncthreads();
  }

  if (BF16_OUT) {
    unsigned short* C = (unsigned short*)Cout;
    #pragma unroll
    for (int m = 0; m < 4; m++)
      #pragma unroll
      for (int i = 0; i < 4; i++) {
        size_t r = (size_t)(bm + wr + m * 16 + (ln >> 4) * 4 + i);
        #pragma unroll
        for (int n = 0; n < 4; n++)
          C[r * N + bn + wc + n * 16 + (ln & 15)] = f2bf(acc[m][n][i]);
      }
  } else {
    float* C = (float*)Cout;
    float bv[4];
    #pragma unroll
    for (int n = 0; n < 4; n++)
      bv[n] = bias ? bias[bn + wc + n * 16 + (ln & 15)] : 0.f;
    #pragma unroll
    for (int m = 0; m < 4; m++)
      #pragma unroll
      for (int i = 0; i < 4; i++) {
        size_t r = (size_t)(bm + wr + m * 16 + (ln >> 4) * 4 + i);
        #pragma unroll
        for (int n = 0; n < 4; n++)
          C[r * N + bn + wc + n * 16 + (ln & 15)] = acc[m][n][i] + bv[n];
      }
  }
}

// ------------------------------------------------- M^T = scale*(k^T v)^T ---
// one block per (b, h, half); M over j in that half; stored transposed [d][e]
__global__ __launch_bounds__(256) void kv_outer(
    const unsigned short* __restrict__ qkv,
    unsigned short* __restrict__ MT, float scale) {
  const int bid = blockIdx.x;                 // b*32 + h*2 + half
  const int b = bid >> 5, h = (bid >> 1) & 15, hf = bid & 1;
  const size_t base = ((size_t)(b * 2048 + hf * 1024)) * 3072 + h * 64;
  const unsigned short* kp = qkv + base + 1024;
  const unsigned short* vp = qkv + base + 2048;
  __shared__ __align__(16) unsigned short kT[64][136];   // 272B rows, 16B aligned
  __shared__ __align__(16) unsigned short vT[64][136];
  const int tid = threadIdx.x, wv = tid >> 6, ln = tid & 63;
  f32x4 acc[4] = {};
  const int e4 = (tid & 15) * 4;     // e block for transpose staging
  const int jr = tid >> 4;           // 0..15
  const int fr = ln & 15, ko = (ln >> 4) * 8;

  for (int j0 = 0; j0 < 1024; j0 += 128) {
    __syncthreads();
    #pragma unroll
    for (int jj = 0; jj < 128; jj += 16) {
      int j = jj + jr;
      size_t go = (size_t)(j0 + j) * 3072 + e4;
      short4v k4 = *(const short4v*)(kp + go);
      short4v v4 = *(const short4v*)(vp + go);
      #pragma unroll
      for (int t = 0; t < 4; t++) {
        kT[e4 + t][j] = (unsigned short)k4[t];
        vT[e4 + t][j] = (unsigned short)v4[t];
      }
    }
    __syncthreads();
    #pragma unroll
    for (int kk = 0; kk < 128; kk += 32) {
      bf16x8 af = *(const bf16x8*)&kT[wv * 16 + fr][kk + ko];
      #pragma unroll
      for (int n = 0; n < 4; n++) {
        bf16x8 bf2 = *(const bf16x8*)&vT[n * 16 + fr][kk + ko];
        acc[n] = __builtin_amdgcn_mfma_f32_16x16x32_bf16(af, bf2, acc[n], 0, 0, 0);
      }
    }
  }
  unsigned short* outp = MT + (size_t)bid * 4096;       // [d][e], 64x64
  #pragma unroll
  for (int n = 0; n < 4; n++)
    #pragma unroll
    for (int i = 0; i < 4; i++) {
      int d = n * 16 + fr;
      int e = wv * 16 + (ln >> 4) * 4 + i;
      outp[d * 64 + e] = f2bf(acc[n][i] * scale);
    }
}

// ------------------------------------------------------------ o = q * M ----
__global__ __launch_bounds__(256) void apply_q(
    const unsigned short* __restrict__ qkv,
    const unsigned short* __restrict__ MT,
    unsigned short* __restrict__ o) {
  const int bid = blockIdx.x;     // ((b*16+h)*2 + lhalf)*16 + lt
  const int lt = bid & 15, hf = (bid >> 4) & 1, h = (bid >> 5) & 15, b = bid >> 9;
  const int l0 = hf * 1024 + lt * 64;
  const unsigned short* qp = qkv + ((size_t)(b * 2048 + l0)) * 3072 + h * 64;
  const unsigned short* mp = MT + ((size_t)((b * 16 + h) * 2 + (1 - hf))) * 4096;
  const int tid = threadIdx.x, wv = tid >> 6, ln = tid & 63;
  const int fr = ln & 15, ko = (ln >> 4) * 8;
  f32x4 acc[4] = {};
  #pragma unroll
  for (int kk = 0; kk < 2; kk++) {
    bf16x8 af = *(const bf16x8*)(qp + (size_t)(wv * 16 + fr) * 3072 + kk * 32 + ko);
    #pragma unroll
    for (int n = 0; n < 4; n++) {
      bf16x8 bf2 = *(const bf16x8*)(mp + (n * 16 + fr) * 64 + kk * 32 + ko);
      acc[n] = __builtin_amdgcn_mfma_f32_16x16x32_bf16(af, bf2, acc[n], 0, 0, 0);
    }
  }
  unsigned short* op = o + ((size_t)(b * 2048 + l0)) * 1024 + h * 64;
  #pragma unroll
  for (int n = 0; n < 4; n++)
    #pragma unroll
    for (int i = 0; i < 4; i++)
      op[(size_t)(wv * 16 + (ln >> 4) * 4 + i) * 1024 + n * 16 + fr] = f2bf(acc[n][i]);
}

// ---------------------------------------------------------------------------
extern "C" void kernel_launch(void* const* d_in, const int* in_sizes, int n_in,
                              void* d_out, int out_size, void* d_ws, size_t ws_size,
                              hipStream_t stream) {
  const float* x     = (const float*)d_in[0];   // 4 x 2048 x 1024
  const float* Wqkv  = (const float*)d_in[1];   // 1024 x 3072
  const float* Wproj = (const float*)d_in[2];   // 1024 x 1024
  const float* bproj = (const float*)d_in[3];   // 1024
  float* out = (float*)d_out;                   // 8192 x 1024

  char* ws = (char*)d_ws;
  unsigned short* xb     = (unsigned short*)(ws);               // 16.78 MB
  unsigned short* wqkvT  = (unsigned short*)(ws + 16777216);    //  6.29 MB
  unsigned short* wprojT = (unsigned short*)(ws + 23068672);    //  2.10 MB
  unsigned short* qkv    = (unsigned short*)(ws + 25165824);    // 50.33 MB
  unsigned short* MT     = (unsigned short*)(ws + 75497472);    //  1.05 MB
  unsigned short* ob     = (unsigned short*)(ws + 76546048);    // 16.78 MB

  // casts / transposes
  cast4_bf16<<<8192, 256, 0, stream>>>(x, xb, 2097152);
  transpose_cast<<<dim3(96, 32), 256, 0, stream>>>(Wqkv, wqkvT, 1024, 3072);
  transpose_cast<<<dim3(32, 32), 256, 0, stream>>>(Wproj, wprojT, 1024, 1024);

  // qkv = x @ W_qkv   (8192 x 3072, bf16 out)
  gemm_bt<1><<<dim3(24, 64), 256, 0, stream>>>(xb, wqkvT, (void*)qkv, nullptr,
                                               8192, 3072, 1024);
  // M^T = scale * (k^T v)^T per (b,h,half)
  kv_outer<<<128, 256, 0, stream>>>(qkv, MT, 0.125f);
  // o = q @ M(other half)
  apply_q<<<2048, 256, 0, stream>>>(qkv, MT, ob);
  // out = o @ W_proj + b  (fp32 out)
  gemm_bt<0><<<dim3(8, 64), 256, 0, stream>>>(ob, wprojT, (void*)out, bproj,
                                              8192, 1024, 1024);
}